// Round 1
// baseline (461.877 us; speedup 1.0000x reference)
//
#include <hip/hip_runtime.h>
#include <cmath>

// Problem constants
static constexpr int B_  = 16;
static constexpr int N_  = 2048;
static constexpr int NT_ = 32768;     // B_*N_
static constexpr int E_  = 524288;    // NT_*16
static constexpr int CIN = 64;
static constexpr int HID = 128;
static constexpr int KK  = 32;

// Workspace layout (float offsets)
static constexpr size_t OFF_H      = 0;          // NT_*64
static constexpr size_t OFF_AGG    = 2097152;    // NT_*64
static constexpr size_t OFF_XD     = 4194304;    // NT_*128
static constexpr size_t OFF_SWS    = 8388608;    // NT_*32
static constexpr size_t OFF_PART   = 9437184;    // 8*B_*KK*HID = 524288
static constexpr size_t OFF_DEGIN  = 9961472;    // NT_
static constexpr size_t OFF_DEGOUT = 9994240;    // NT_
static constexpr size_t OFF_DINV   = 10027008;   // NT_
static constexpr size_t OFF_SHIFT  = 10059776;   // B_*64
static constexpr size_t OFF_SCALE  = 10060800;   // B_*64
static constexpr size_t OFF_CA     = 10061824;   // B_*32
static constexpr size_t OFF_CS     = 10062336;   // B_*32
static constexpr size_t OFF_SS     = 10062848;   // B_*1024
static constexpr size_t OFF_SPECA  = 10079232;   // B_
static constexpr size_t OFF_MTOT   = 10079248;   // B_
static constexpr size_t OFF_GSUM   = 10079264;   // B_*64
static constexpr size_t OFF_GSUM2  = 10080288;   // B_*64
// total 10081312 floats = 38.5 MiB

__device__ __forceinline__ float selu_f(float x) {
  return 1.0507009873554805f * (x > 0.f ? x : 1.6732632423543772f * expm1f(x));
}

__device__ __forceinline__ float block_sum_bcast(float v, float* sm) {
  int lane = threadIdx.x & 63, w = threadIdx.x >> 6;
#pragma unroll
  for (int off = 32; off; off >>= 1) v += __shfl_down(v, off);
  __syncthreads();
  if (lane == 0) sm[w] = v;
  __syncthreads();
  return sm[0] + sm[1] + sm[2] + sm[3];
}

// ---- init ----
__global__ void k_zero_agg(float* agg) {          // grid 2048 x 256 -> 524288 float4
  int i = blockIdx.x * 256 + threadIdx.x;
  float4 z = {0.f, 0.f, 0.f, 0.f};
  ((float4*)agg)[i] = z;
}

__global__ void k_init_small(float* degin, float* degout, float* ss, float* gsum,
                             float* gsum2, float* ca, float* cs, float* specA,
                             float* mtot, float* lossp) {  // grid 128 x 256 = 32768
  int i = blockIdx.x * 256 + threadIdx.x;
  degin[i] = 1.f;   // self-loop
  degout[i] = 0.f;
  if (i < 16384) ss[i] = 0.f;
  if (i < 1024) { gsum[i] = 0.f; gsum2[i] = 0.f; }
  if (i < 512)  { ca[i] = 0.f; cs[i] = 0.f; }
  if (i < 16)   { specA[i] = 0.f; mtot[i] = 0.f; }
  if (i == 0)   lossp[0] = 0.f;
}

// ---- degree counting ----
__global__ void k_deg(const int* ei, float* degin, float* degout) {  // grid 2048 x 256
  int e = blockIdx.x * 256 + threadIdx.x;
  atomicAdd(&degout[ei[e]], 1.f);        // src row (adj row-sum degrees)
  atomicAdd(&degin[ei[E_ + e]], 1.f);    // dst (GCN deg, on top of self-loop 1)
}

// ---- GraphNorm stats ----
__global__ void k_gn_part(const float* x, float* gsum, float* gsum2) { // grid 128 x 256
  int b = blockIdx.x >> 3, chunk = blockIdx.x & 7;
  int c = threadIdx.x & 63, r = threadIdx.x >> 6;
  float s = 0.f, s2 = 0.f;
  const float* xb = x + ((size_t)b * N_ + (size_t)chunk * 256) * 64;
  for (int n = r; n < 256; n += 4) {
    float v = xb[n * 64 + c];
    s += v; s2 += v * v;
  }
  __shared__ float l1[4][64], l2[4][64];
  l1[r][c] = s; l2[r][c] = s2;
  __syncthreads();
  if (r == 0) {
    s  = l1[0][c] + l1[1][c] + l1[2][c] + l1[3][c];
    s2 = l2[0][c] + l2[1][c] + l2[2][c] + l2[3][c];
    atomicAdd(&gsum[b * 64 + c], s);
    atomicAdd(&gsum2[b * 64 + c], s2);
  }
}

__global__ void k_gn_fin(const float* gsum, const float* gsum2, const float* gw,
                         const float* gms, float* shift, float* scalev) { // grid 4 x 256
  int i = blockIdx.x * 256 + threadIdx.x;  // < 1024
  int c = i & 63;
  float mean = gsum[i] * (1.f / 2048.f);
  float a = gms[c];
  float var = gsum2[i] * (1.f / 2048.f) - (2.f * a - a * a) * mean * mean;
  shift[i] = a * mean;
  scalev[i] = gw[c] * rsqrtf(var + 1e-5f);
}

// ---- h = graphnorm(x), dinv = rsqrt(deg) ----
__global__ void k_h(const float* x, const float* shift, const float* scalev,
                    const float* gb, const float* degin, float* h, float* dinv) {
  int idx = blockIdx.x * 256 + threadIdx.x;  // grid 2048 x 256 = NT_*16
  int node = idx >> 4, g4 = (idx & 15) * 4;
  int b = node >> 11;
  float4 xv = *(const float4*)&x[node * 64 + g4];
  float4 sh = *(const float4*)&shift[b * 64 + g4];
  float4 sc = *(const float4*)&scalev[b * 64 + g4];
  float4 bb = *(const float4*)&gb[g4];
  float4 o;
  o.x = (xv.x - sh.x) * sc.x + bb.x;
  o.y = (xv.y - sh.y) * sc.y + bb.y;
  o.z = (xv.z - sh.z) * sc.z + bb.z;
  o.w = (xv.w - sh.w) * sc.w + bb.w;
  *(float4*)&h[node * 64 + g4] = o;
  if (idx < NT_) dinv[idx] = rsqrtf(degin[idx]);
}

// ---- edge scatter: agg[dst] += dinv[s]*dinv[d]*h[src] ----
__global__ void k_scatter(const int* ei, const float* h, const float* dinv, float* agg) {
  int idx = blockIdx.x * 256 + threadIdx.x;  // grid 131072 x 256 = E_*64
  int e = idx >> 6, c = idx & 63;
  int s = ei[e], d = ei[E_ + e];
  float w = dinv[s] * dinv[d];
  atomicAdd(&agg[d * 64 + c], w * h[s * 64 + c]);
}

// ---- xd = selu((agg + dinv^2*h) @ w1 + b1) ----
__global__ __launch_bounds__(256) void k_mm1(const float* agg, const float* h,
                                             const float* dinv, const float* w1,
                                             const float* b1, float* xd) {
  __shared__ float w1s[64 * 128];   // 32 KB
  __shared__ float at[32 * 65];     // padded a-tile
  int tid = threadIdx.x;
  for (int i = tid; i < 8192; i += 256) w1s[i] = w1[i];
  int n0 = blockIdx.x * 32;         // grid 1024
  for (int i = tid; i < 2048; i += 256) {
    int n = i >> 6, k = i & 63;
    int node = n0 + n;
    float di = dinv[node];
    at[n * 65 + k] = agg[node * 64 + k] + di * di * h[node * 64 + k];
  }
  __syncthreads();
  int tx = tid & 31, ty = tid >> 5;
  int f0 = tx * 4, nn = ty * 4;
  float acc[4][4] = {};
  for (int k = 0; k < 64; k++) {
    float4 wv = *(float4*)&w1s[k * 128 + f0];
#pragma unroll
    for (int i = 0; i < 4; i++) {
      float av = at[(nn + i) * 65 + k];
      acc[i][0] += av * wv.x; acc[i][1] += av * wv.y;
      acc[i][2] += av * wv.z; acc[i][3] += av * wv.w;
    }
  }
  float4 bv = *(const float4*)&b1[f0];
#pragma unroll
  for (int i = 0; i < 4; i++) {
    float4 o;
    o.x = selu_f(acc[i][0] + bv.x);
    o.y = selu_f(acc[i][1] + bv.y);
    o.z = selu_f(acc[i][2] + bv.z);
    o.w = selu_f(acc[i][3] + bv.w);
    *(float4*)&xd[(size_t)(n0 + nn + i) * 128 + f0] = o;
  }
}

// ---- s = softmax(xd @ w2 + b2) ----
__global__ __launch_bounds__(256) void k_mm2s(const float* xd, const float* w2,
                                              const float* b2, float* s_ws) {
  __shared__ float w2s[128 * 32];   // 16 KB
  __shared__ float xt[64 * 129];    // 33 KB
  __shared__ float lg[64 * 33];     // 8.4 KB
  int tid = threadIdx.x;
  for (int i = tid; i < 4096; i += 256) w2s[i] = w2[i];
  int n0 = blockIdx.x * 64;         // grid 512
  for (int i = tid; i < 2048; i += 256) {
    int n = i >> 5, j4 = (i & 31) * 4;
    float4 v = *(const float4*)&xd[(size_t)(n0 + n) * 128 + j4];
    xt[n * 129 + j4] = v.x; xt[n * 129 + j4 + 1] = v.y;
    xt[n * 129 + j4 + 2] = v.z; xt[n * 129 + j4 + 3] = v.w;
  }
  __syncthreads();
  int tx = tid & 7, ty = tid >> 3;
  int k0 = tx * 4;
  float acc[2][4] = {};
  for (int j = 0; j < 128; j++) {
    float4 wv = *(float4*)&w2s[j * 32 + k0];
    float x0 = xt[(ty * 2) * 129 + j];
    float x1 = xt[(ty * 2 + 1) * 129 + j];
    acc[0][0] += x0 * wv.x; acc[0][1] += x0 * wv.y; acc[0][2] += x0 * wv.z; acc[0][3] += x0 * wv.w;
    acc[1][0] += x1 * wv.x; acc[1][1] += x1 * wv.y; acc[1][2] += x1 * wv.z; acc[1][3] += x1 * wv.w;
  }
  float4 bv = *(const float4*)&b2[k0];
#pragma unroll
  for (int i = 0; i < 2; i++) {
    int n = ty * 2 + i;
    lg[n * 33 + k0]     = acc[i][0] + bv.x;
    lg[n * 33 + k0 + 1] = acc[i][1] + bv.y;
    lg[n * 33 + k0 + 2] = acc[i][2] + bv.z;
    lg[n * 33 + k0 + 3] = acc[i][3] + bv.w;
  }
  __syncthreads();
  if (tid < 64) {
    float m = -3.4e38f;
    for (int kk = 0; kk < 32; kk++) m = fmaxf(m, lg[tid * 33 + kk]);
    float ssum = 0.f;
    for (int kk = 0; kk < 32; kk++) {
      float e = expf(lg[tid * 33 + kk] - m);
      lg[tid * 33 + kk] = e; ssum += e;
    }
    float inv = 1.f / ssum;
    for (int k4 = 0; k4 < 32; k4 += 4) {
      float4 o;
      o.x = lg[tid * 33 + k4] * inv;     o.y = lg[tid * 33 + k4 + 1] * inv;
      o.z = lg[tid * 33 + k4 + 2] * inv; o.w = lg[tid * 33 + k4 + 3] * inv;
      *(float4*)&s_ws[(size_t)(n0 + tid) * 32 + k4] = o;
    }
  }
}

// ---- copy s to output (output region is 4B- but not 16B-aligned) ----
__global__ void k_copy_s(const float* s_ws, float* outs) {  // grid 4096 x 256
  int i = blockIdx.x * 256 + threadIdx.x;
  outs[i] = s_ws[i];
}

// ---- ca[b,k]=sum s*degout, csize[b,k]=sum s, mtot[b]=sum degout ----
__global__ void k_ca(const float* s_ws, const float* degout, float* ca,
                     float* cs, float* mtot) {   // grid 128 x 256
  int b = blockIdx.x >> 3, chunk = blockIdx.x & 7;
  int k = threadIdx.x & 31, r = threadIdx.x >> 5;
  float aca = 0.f, acs = 0.f, am = 0.f;
  int nbase = b * 2048 + chunk * 256;
  for (int i = 0; i < 32; i++) {
    int node = nbase + i * 8 + r;
    float dg = degout[node];
    float v = s_ws[(size_t)node * 32 + k];
    acs += v; aca += v * dg; am += dg;
  }
  __shared__ float r1[8][32], r2[8][32], rm[8];
  r1[r][k] = aca; r2[r][k] = acs;
  if (k == 0) rm[r] = am;
  __syncthreads();
  if (r == 0) {
    float sa = 0.f, sc = 0.f;
#pragma unroll
    for (int i = 0; i < 8; i++) { sa += r1[i][k]; sc += r2[i][k]; }
    atomicAdd(&ca[b * 32 + k], sa);
    atomicAdd(&cs[b * 32 + k], sc);
    if (k == 0) {
      float sm_ = 0.f;
#pragma unroll
      for (int i = 0; i < 8; i++) sm_ += rm[i];
      atomicAdd(&mtot[b], sm_);
    }
  }
}

// ---- trace(S^T A S) per graph via per-edge dot ----
__global__ void k_spec(const int* ei, const float* s_ws, float* specA) { // grid 2048 x 256
  int e = blockIdx.x * 256 + threadIdx.x;
  int s = ei[e], d = ei[E_ + e];
  const float4* a = (const float4*)&s_ws[(size_t)s * 32];
  const float4* c = (const float4*)&s_ws[(size_t)d * 32];
  float acc = 0.f;
#pragma unroll
  for (int i = 0; i < 8; i++) {
    float4 u = a[i], v = c[i];
    acc += u.x * v.x + u.y * v.y + u.z * v.z + u.w * v.w;
  }
#pragma unroll
  for (int off = 32; off; off >>= 1) acc += __shfl_down(acc, off);
  if ((threadIdx.x & 63) == 0) atomicAdd(&specA[blockIdx.x >> 7], acc);
}

// ---- ss[b] = S^T S ----
__global__ __launch_bounds__(256) void k_ss(const float* s_ws, float* ss) { // grid 128
  __shared__ float st[64 * 33];
  int b = blockIdx.x >> 3, chunk = blockIdx.x & 7;
  int tid = threadIdx.x;
  int k = tid >> 3, l0 = (tid & 7) * 4;
  float acc[4] = {};
  for (int sub = 0; sub < 4; sub++) {
    int base = b * 2048 + chunk * 256 + sub * 64;
    __syncthreads();
    for (int i = tid; i < 2048; i += 256) {
      int n = i >> 5, kk = i & 31;
      st[n * 33 + kk] = s_ws[(size_t)(base + n) * 32 + kk];
    }
    __syncthreads();
    for (int n = 0; n < 64; n++) {
      float sk = st[n * 33 + k];
      acc[0] += sk * st[n * 33 + l0];
      acc[1] += sk * st[n * 33 + l0 + 1];
      acc[2] += sk * st[n * 33 + l0 + 2];
      acc[3] += sk * st[n * 33 + l0 + 3];
    }
  }
  atomicAdd(&ss[b * 1024 + k * 32 + l0], acc[0]);
  atomicAdd(&ss[b * 1024 + k * 32 + l0 + 1], acc[1]);
  atomicAdd(&ss[b * 1024 + k * 32 + l0 + 2], acc[2]);
  atomicAdd(&ss[b * 1024 + k * 32 + l0 + 3], acc[3]);
}

// ---- partial out[b,k,f] = sum_n s[n,k]*xd[n,f] over 256-node chunk ----
__global__ __launch_bounds__(256) void k_outp(const float* s_ws, const float* xd,
                                              float* partial) {  // grid 128
  __shared__ float st[64 * 36];   // 9.2 KB (stride 36 keeps float4 alignment)
  __shared__ float xt[64 * 132];  // 33.8 KB
  int b = blockIdx.x & 15, chunk = blockIdx.x >> 4;
  int tid = threadIdx.x;
  int tx = tid & 31, ty = tid >> 5;
  int f0 = tx * 4, k0 = ty * 4;
  float acc[4][4] = {};
  for (int sub = 0; sub < 4; sub++) {
    int base = b * 2048 + chunk * 256 + sub * 64;
    __syncthreads();
    for (int i = tid; i < 2048; i += 256) {
      int n = i >> 5, kk = i & 31;
      st[n * 36 + kk] = s_ws[(size_t)(base + n) * 32 + kk];
    }
    for (int i = tid; i < 8192; i += 256) {
      int n = i >> 7, j = i & 127;
      xt[n * 132 + j] = xd[(size_t)(base + n) * 128 + j];
    }
    __syncthreads();
    for (int n = 0; n < 64; n++) {
      float4 sv = *(float4*)&st[n * 36 + k0];
      float4 xv = *(float4*)&xt[n * 132 + f0];
      acc[0][0] += sv.x * xv.x; acc[0][1] += sv.x * xv.y; acc[0][2] += sv.x * xv.z; acc[0][3] += sv.x * xv.w;
      acc[1][0] += sv.y * xv.x; acc[1][1] += sv.y * xv.y; acc[1][2] += sv.y * xv.z; acc[1][3] += sv.y * xv.w;
      acc[2][0] += sv.z * xv.x; acc[2][1] += sv.z * xv.y; acc[2][2] += sv.z * xv.z; acc[2][3] += sv.z * xv.w;
      acc[3][0] += sv.w * xv.x; acc[3][1] += sv.w * xv.y; acc[3][2] += sv.w * xv.z; acc[3][3] += sv.w * xv.w;
    }
  }
  int pbase = (chunk * 16 + b) * 32;
#pragma unroll
  for (int i = 0; i < 4; i++) {
    float4 o = {acc[i][0], acc[i][1], acc[i][2], acc[i][3]};
    *(float4*)&partial[(size_t)(pbase + k0 + i) * 128 + f0] = o;
  }
}

// ---- reduce partials, selu, log_softmax over F=128 ----
__global__ void k_outf(const float* partial, float* out0) {  // grid 512 x 128
  int row = blockIdx.x;
  int b = row >> 5, k = row & 31;
  int f = threadIdx.x;
  float v = 0.f;
#pragma unroll
  for (int c = 0; c < 8; c++) v += partial[(size_t)(((c * 16 + b) * 32 + k)) * 128 + f];
  v = selu_f(v);
  int lane = threadIdx.x & 63, w = threadIdx.x >> 6;
  __shared__ float s1[2], s2[2];
  float m = v;
#pragma unroll
  for (int off = 32; off; off >>= 1) m = fmaxf(m, __shfl_down(m, off));
  if (lane == 0) s1[w] = m;
  __syncthreads();
  m = fmaxf(s1[0], s1[1]);
  float e = expf(v - m), t = e;
#pragma unroll
  for (int off = 32; off; off >>= 1) t += __shfl_down(t, off);
  if (lane == 0) s2[w] = t;
  __syncthreads();
  float tot = s2[0] + s2[1];
  out0[(size_t)row * 128 + f] = v - m - logf(tot);
}

// ---- per-graph losses ----
__global__ void k_loss(const float* ss, const float* cs, const float* ca,
                       const float* specA, const float* mtot, float* loss) { // grid 16 x 256
  int b = blockIdx.x;
  __shared__ float sm[4];
  float ssq = 0.f;
  for (int i = threadIdx.x; i < 1024; i += 256) {
    float v = ss[b * 1024 + i]; ssq += v * v;
  }
  ssq = block_sum_bcast(ssq, sm);
  float inv = 1.f / sqrtf(ssq);
  float dsq = 0.f;
  for (int i = threadIdx.x; i < 1024; i += 256) {
    float v = ss[b * 1024 + i] * inv;
    if ((i >> 5) == (i & 31)) v -= 0.17677669529663687f;  // 1/sqrt(32)
    dsq += v * v;
  }
  dsq = block_sum_bcast(dsq, sm);
  float csq = 0.f, casq = 0.f;
  if (threadIdx.x < 32) {
    float c1 = cs[b * 32 + threadIdx.x]; csq = c1 * c1;
    float c2 = ca[b * 32 + threadIdx.x]; casq = c2 * c2;
  }
  csq = block_sum_bcast(csq, sm);
  casq = block_sum_bcast(casq, sm);
  if (threadIdx.x == 0) {
    float ortho = sqrtf(dsq);
    float cl = sqrtf(csq) * (1.f / 2048.f) * 5.656854249492381f - 1.f;  // *sqrt(32)
    float m = mtot[b] * 0.5f;
    float spec = -(specA[b] - casq / (2.f * m)) / (2.f * m);
    atomicAdd(loss, (spec + ortho + cl) * (1.f / 16.f));
  }
}

extern "C" void kernel_launch(void* const* d_in, const int* in_sizes, int n_in,
                              void* d_out, int out_size, void* d_ws, size_t ws_size,
                              hipStream_t stream) {
  (void)in_sizes; (void)n_in; (void)out_size; (void)ws_size;
  const float* x   = (const float*)d_in[0];
  const int*   ei  = (const int*)d_in[1];
  // d_in[2] = batch (uniform sizes -> unused)
  const float* gw  = (const float*)d_in[3];
  const float* gb  = (const float*)d_in[4];
  const float* gms = (const float*)d_in[5];
  const float* w1  = (const float*)d_in[6];
  const float* b1  = (const float*)d_in[7];
  const float* w2  = (const float*)d_in[8];
  const float* b2  = (const float*)d_in[9];
  float* out = (float*)d_out;
  float* ws  = (float*)d_ws;

  float* h      = ws + OFF_H;
  float* agg    = ws + OFF_AGG;
  float* xd     = ws + OFF_XD;
  float* s_ws   = ws + OFF_SWS;
  float* part   = ws + OFF_PART;
  float* degin  = ws + OFF_DEGIN;
  float* degout = ws + OFF_DEGOUT;
  float* dinv   = ws + OFF_DINV;
  float* shift  = ws + OFF_SHIFT;
  float* scalev = ws + OFF_SCALE;
  float* ca     = ws + OFF_CA;
  float* cs     = ws + OFF_CS;
  float* ssb    = ws + OFF_SS;
  float* specA  = ws + OFF_SPECA;
  float* mtot   = ws + OFF_MTOT;
  float* gsum   = ws + OFF_GSUM;
  float* gsum2  = ws + OFF_GSUM2;

  float* out0  = out;            // [B,K,HID] log_softmax
  float* lossp = out + 65536;    // scalar
  float* outs  = out + 65537;    // [B,N,K] s

  hipLaunchKernelGGL(k_zero_agg, dim3(2048), dim3(256), 0, stream, agg);
  hipLaunchKernelGGL(k_init_small, dim3(128), dim3(256), 0, stream,
                     degin, degout, ssb, gsum, gsum2, ca, cs, specA, mtot, lossp);
  hipLaunchKernelGGL(k_deg, dim3(2048), dim3(256), 0, stream, ei, degin, degout);
  hipLaunchKernelGGL(k_gn_part, dim3(128), dim3(256), 0, stream, x, gsum, gsum2);
  hipLaunchKernelGGL(k_gn_fin, dim3(4), dim3(256), 0, stream, gsum, gsum2, gw, gms, shift, scalev);
  hipLaunchKernelGGL(k_h, dim3(2048), dim3(256), 0, stream, x, shift, scalev, gb, degin, h, dinv);
  hipLaunchKernelGGL(k_scatter, dim3(131072), dim3(256), 0, stream, ei, h, dinv, agg);
  hipLaunchKernelGGL(k_mm1, dim3(1024), dim3(256), 0, stream, agg, h, dinv, w1, b1, xd);
  hipLaunchKernelGGL(k_mm2s, dim3(512), dim3(256), 0, stream, xd, w2, b2, s_ws);
  hipLaunchKernelGGL(k_copy_s, dim3(4096), dim3(256), 0, stream, s_ws, outs);
  hipLaunchKernelGGL(k_ca, dim3(128), dim3(256), 0, stream, s_ws, degout, ca, cs, mtot);
  hipLaunchKernelGGL(k_spec, dim3(2048), dim3(256), 0, stream, ei, s_ws, specA);
  hipLaunchKernelGGL(k_ss, dim3(128), dim3(256), 0, stream, s_ws, ssb);
  hipLaunchKernelGGL(k_outp, dim3(128), dim3(256), 0, stream, s_ws, xd, part);
  hipLaunchKernelGGL(k_outf, dim3(512), dim3(128), 0, stream, part, out0);
  hipLaunchKernelGGL(k_loss, dim3(16), dim3(256), 0, stream, ssb, cs, ca, specA, mtot, lossp);
}